// Round 17
// baseline (389.233 us; speedup 1.0000x reference)
//
#include <hip/hip_runtime.h>
#include <hip/hip_bf16.h>

#define K 9
#define C 32
#define H 8
#define DV 8
#define DE 64
#define DIN 128
#define KC 288   // K*C
#define HD 64    // H*DV
#define MS 576   // K*HD

typedef unsigned short u16;
typedef unsigned int u32;
typedef __fp16 f16;
typedef f16 f16x8 __attribute__((ext_vector_type(8)));
typedef f16 f16x2 __attribute__((ext_vector_type(2)));
typedef float f32x4 __attribute__((ext_vector_type(4)));
typedef float f32x2 __attribute__((ext_vector_type(2)));

__device__ __forceinline__ f16x8 pack8(float4 a, float4 b){
  union { f16x8 v; f16x2 h[4]; } u;
  u.h[0] = __builtin_amdgcn_cvt_pkrtz(a.x, a.y);
  u.h[1] = __builtin_amdgcn_cvt_pkrtz(a.z, a.w);
  u.h[2] = __builtin_amdgcn_cvt_pkrtz(b.x, b.y);
  u.h[3] = __builtin_amdgcn_cvt_pkrtz(b.z, b.w);
  return u.v;
}

__device__ __forceinline__ f16x8 loadWfrag(const float* __restrict__ W, int k0, int col){
  union { f16x8 v; f16x2 h[4]; } u;
  #pragma unroll
  for (int j = 0; j < 4; ++j){
    float x0 = W[(k0 + 2*j    )*DE + col];
    float x1 = W[(k0 + 2*j + 1)*DE + col];
    u.h[j] = __builtin_amdgcn_cvt_pkrtz(x0, x1);
  }
  return u.v;
}

// ---- CSR build
__global__ void k_count(const int* __restrict__ dst, int* __restrict__ counts, int Ee){
  int e = blockIdx.x*blockDim.x + threadIdx.x;
  if (e < Ee) atomicAdd(&counts[dst[e]], 1);
}

__global__ void k_scan(const int* __restrict__ counts, int* __restrict__ rowptr,
                       int* __restrict__ rowpos, int Nn, int Ee){
  __shared__ int part[1024];
  int t = threadIdx.x;
  int cpt = (Nn + 1023) >> 10;
  int base = t*cpt;
  int lsum = 0;
  for (int i = 0; i < cpt; ++i){ int idx = base+i; if (idx < Nn) lsum += counts[idx]; }
  part[t] = lsum; __syncthreads();
  for (int off = 1; off < 1024; off <<= 1){
    int v = (t >= off) ? part[t-off] : 0;
    __syncthreads();
    part[t] += v;
    __syncthreads();
  }
  int run = part[t] - lsum;
  for (int i = 0; i < cpt; ++i){
    int idx = base+i;
    if (idx < Nn){ rowptr[idx] = run; rowpos[idx] = run; run += counts[idx]; }
  }
  if (t == 1023) rowptr[Nn] = Ee;
}

__global__ void k_scatter(const int* __restrict__ src, const int* __restrict__ dst,
                          int* __restrict__ rowpos, int* __restrict__ esrc,
                          int* __restrict__ epos, int Ee){
  int e = blockIdx.x*blockDim.x + threadIdx.x;
  if (e >= Ee) return;
  int pos = atomicAdd(&rowpos[dst[e]], 1);
  esrc[pos] = src[e];
  epos[e] = pos;
}

// ---- 2. per-node (eqnorm fused): V packed fp8-e4m3 [n][3][64]; ps/pd logit halves
__global__ void k_value(const float* __restrict__ nf, const float* __restrict__ ln1g,
                        const float* __restrict__ Wv, const float* __restrict__ Wa,
                        const float* __restrict__ ba,
                        u32* __restrict__ V32, float* __restrict__ psb,
                        float* __restrict__ pdb, int Nn){
  __shared__ float xsL[4][KC];
  __shared__ float scL[4][C];
  int lane = threadIdx.x & 63, w = threadIdx.x >> 6;
  int n = blockIdx.x*4 + w;
  if (n >= Nn) return;
  {
    const float* xb = nf + (size_t)n*KC;
    for (int i = lane; i < KC; i += 64) xsL[w][i] = xb[i];
  }
  asm volatile("s_waitcnt lgkmcnt(0)" ::: "memory");
  if (lane < 32){
    float ss = 0.f;
    #pragma unroll
    for (int k = 0; k < K; ++k){ float v = xsL[w][k*C + lane]; ss += v*v; }
    scL[w][lane] = ln1g[lane] / sqrtf(ss*(1.0f/K) + 1e-6f);
  }
  asm volatile("s_waitcnt lgkmcnt(0)" ::: "memory");
  {
    for (int i = lane; i < KC; i += 64) xsL[w][i] *= scL[w][i & 31];
  }
  asm volatile("s_waitcnt lgkmcnt(0)" ::: "memory");
  int dd = lane;
  float acc[K];
  #pragma unroll
  for (int k = 0; k < K; ++k) acc[k] = 0.f;
  for (int c = 0; c < C; ++c){
    float wvc = Wv[c*HD + dd];
    #pragma unroll
    for (int k = 0; k < K; ++k) acc[k] += xsL[w][k*C + c] * wvc;
  }
  u32 w0 = __builtin_amdgcn_cvt_pk_fp8_f32(acc[0], acc[1], 0, false);
  w0     = __builtin_amdgcn_cvt_pk_fp8_f32(acc[2], acc[3], w0, true);
  u32 w1 = __builtin_amdgcn_cvt_pk_fp8_f32(acc[4], acc[5], 0, false);
  w1     = __builtin_amdgcn_cvt_pk_fp8_f32(acc[6], acc[7], w1, true);
  u32 w2 = __builtin_amdgcn_cvt_pk_fp8_f32(acc[8], 0.f, 0, false);
  u32* vb = V32 + (size_t)n*192 + dd;
  vb[0] = w0; vb[64] = w1; vb[128] = w2;

  int h = lane >> 3, i = lane & 7;
  float ps = 0.f, pd = 0.f;
  #pragma unroll
  for (int t = 0; t < 4; ++t){
    int c = i + t*8;
    float xv = xsL[w][c];
    ps = fmaf(xv, Wa[c*H + h], ps);
    pd = fmaf(xv, Wa[(32+c)*H + h], pd);
  }
  ps += __shfl_xor(ps, 1); pd += __shfl_xor(pd, 1);
  ps += __shfl_xor(ps, 2); pd += __shfl_xor(pd, 2);
  ps += __shfl_xor(ps, 4); pd += __shfl_xor(pd, 4);
  if (i == 0){
    psb[(size_t)n*H + h] = ps + ba[h];
    pdb[(size_t)n*H + h] = pd;
  }
}

// ---- 3. logits -> z written at CSR position (sequential reads in k_node)
__global__ __launch_bounds__(256)
void k_logits(const float* __restrict__ ef, const int* __restrict__ src,
              const int* __restrict__ dst, const int* __restrict__ epos,
              const float* __restrict__ Wa,
              const float* __restrict__ psb, const float* __restrict__ pdb,
              float* __restrict__ zs, int Ee){
  __shared__ float efL[32*66];
  int t = threadIdx.x;
  int h = t & 7, es = t >> 3;
  float w2r[64];
  #pragma unroll
  for (int d = 0; d < 64; ++d) w2r[d] = Wa[(64+d)*H + h];
  for (int e0 = blockIdx.x*32; e0 < Ee; e0 += gridDim.x*32){
    #pragma unroll
    for (int u = 0; u < 4; ++u){
      int idx = u*512 + t*2;
      int row = idx >> 6, col = idx & 63;
      if (e0 + row < Ee){
        float2 v = *(const float2*)&ef[(size_t)(e0+row)*DE + col];
        *(float2*)&efL[row*66 + col] = v;
      }
    }
    __syncthreads();
    int e = e0 + es;
    if (e < Ee){
      const float* er = &efL[es*66];
      float a0=0.f, a1=0.f, a2=0.f, a3=0.f;
      #pragma unroll
      for (int d = 0; d < 64; d += 4){
        a0 = fmaf(er[d+0], w2r[d+0], a0);
        a1 = fmaf(er[d+1], w2r[d+1], a1);
        a2 = fmaf(er[d+2], w2r[d+2], a2);
        a3 = fmaf(er[d+3], w2r[d+3], a3);
      }
      int s = src[e], d0 = dst[e];
      float logit = (a0+a1)+(a2+a3) + psb[(size_t)s*H + h] + pdb[(size_t)d0*H + h];
      zs[(size_t)epos[e]*H + h] = __expf(logit);
    }
    __syncthreads();
  }
}

// ---- 4. gather + node update: 2 nodes per wave, edge-interleaved dual stream
__global__ void k_node(const float* __restrict__ nf, const u32* __restrict__ V32,
                       const float* __restrict__ zs, const int* __restrict__ rowptr,
                       const int* __restrict__ esrc,
                       const float* __restrict__ Wo, const float* __restrict__ ln2g,
                       const float* __restrict__ Wg, const float* __restrict__ W1,
                       const float* __restrict__ W2, float* __restrict__ out_node, int Nn){
  __shared__ float msgL[4][2][MS];
  __shared__ float xnL[4][KC];
  __shared__ float fL[4][KC];
  int lane = threadIdx.x & 63, w = threadIdx.x >> 6;
  int n0 = blockIdx.x*8 + w*2;
  if (n0 >= Nn) return;
  bool ok1 = (n0 + 1) < Nn;
  {
    int h = lane >> 3;
    int ra = rowptr[n0],  enda = rowptr[n0+1];
    int rb = 0, endb = 0;
    if (ok1){ rb = enda; endb = rowptr[n0+2]; }
    float dena = 0.f, denb = 0.f;
    float acca[K], accb[K];
    #pragma unroll
    for (int k = 0; k < K; ++k){ acca[k] = 0.f; accb[k] = 0.f; }
    while (ra < enda || rb < endb){
      int ca = enda - ra; ca = (ca > 64) ? 64 : ca; if (ca < 0) ca = 0;
      int cb = endb - rb; cb = (cb > 64) ? 64 : cb; if (cb < 0) cb = 0;
      int my_sa = (lane < ca) ? esrc[ra + lane] : 0;
      int my_sb = (lane < cb) ? esrc[rb + lane] : 0;
      int mx = (ca > cb) ? ca : cb;
      for (int j = 0; j < mx; ++j){
        // stream A
        if (j < ca){
          int s = __shfl(my_sa, j);
          float z = zs[(size_t)(ra + j)*H + h];
          dena += z;
          const u32* vb = V32 + (size_t)s*192 + lane;
          u32 w0 = vb[0], w1 = vb[64], w2 = vb[128];
          f32x2 p01 = __builtin_amdgcn_cvt_pk_f32_fp8(w0, false);
          f32x2 p23 = __builtin_amdgcn_cvt_pk_f32_fp8(w0, true);
          f32x2 p45 = __builtin_amdgcn_cvt_pk_f32_fp8(w1, false);
          f32x2 p67 = __builtin_amdgcn_cvt_pk_f32_fp8(w1, true);
          float p8  = __builtin_amdgcn_cvt_f32_fp8(w2, 0);
          acca[0] = fmaf(z, p01[0], acca[0]);
          acca[1] = fmaf(z, p01[1], acca[1]);
          acca[2] = fmaf(z, p23[0], acca[2]);
          acca[3] = fmaf(z, p23[1], acca[3]);
          acca[4] = fmaf(z, p45[0], acca[4]);
          acca[5] = fmaf(z, p45[1], acca[5]);
          acca[6] = fmaf(z, p67[0], acca[6]);
          acca[7] = fmaf(z, p67[1], acca[7]);
          acca[8] = fmaf(z, p8,     acca[8]);
        }
        // stream B (independent addresses: overlaps A's latency)
        if (j < cb){
          int s = __shfl(my_sb, j);
          float z = zs[(size_t)(rb + j)*H + h];
          denb += z;
          const u32* vb = V32 + (size_t)s*192 + lane;
          u32 w0 = vb[0], w1 = vb[64], w2 = vb[128];
          f32x2 p01 = __builtin_amdgcn_cvt_pk_f32_fp8(w0, false);
          f32x2 p23 = __builtin_amdgcn_cvt_pk_f32_fp8(w0, true);
          f32x2 p45 = __builtin_amdgcn_cvt_pk_f32_fp8(w1, false);
          f32x2 p67 = __builtin_amdgcn_cvt_pk_f32_fp8(w1, true);
          float p8  = __builtin_amdgcn_cvt_f32_fp8(w2, 0);
          accb[0] = fmaf(z, p01[0], accb[0]);
          accb[1] = fmaf(z, p01[1], accb[1]);
          accb[2] = fmaf(z, p23[0], accb[2]);
          accb[3] = fmaf(z, p23[1], accb[3]);
          accb[4] = fmaf(z, p45[0], accb[4]);
          accb[5] = fmaf(z, p45[1], accb[5]);
          accb[6] = fmaf(z, p67[0], accb[6]);
          accb[7] = fmaf(z, p67[1], accb[7]);
          accb[8] = fmaf(z, p8,     accb[8]);
        }
      }
      ra += ca; rb += cb;
    }
    float inva = 1.0f / (dena + 1e-9f);
    #pragma unroll
    for (int k = 0; k < K; ++k) msgL[w][0][k*HD + lane] = acca[k]*inva;
    if (ok1){
      float invb = 1.0f / (denb + 1e-9f);
      #pragma unroll
      for (int k = 0; k < K; ++k) msgL[w][1][k*HD + lane] = accb[k]*invb;
    }
  }
  asm volatile("s_waitcnt lgkmcnt(0)" ::: "memory");
  // ---- phase 2 per node (sequential); all-64-lane half-split + shfl_xor(32)
  int c = lane & 31, half = lane >> 5;
  for (int p = 0; p < 2; ++p){
    int n = n0 + p;
    if (n >= Nn) break;
    const float* mg = &msgL[w][p][0];
    float x[K];
    {
      float a[K];
      #pragma unroll
      for (int k = 0; k < K; ++k) a[k] = 0.f;
      for (int dd = 0; dd < 32; ++dd){
        int d = dd + half*32;
        float wo = Wo[d*C + c];
        #pragma unroll
        for (int k = 0; k < K; ++k) a[k] += mg[k*HD + d] * wo;
      }
      #pragma unroll
      for (int k = 0; k < K; ++k) a[k] += __shfl_xor(a[k], 32);
      const float* nb = nf + (size_t)n*KC + c;
      float ss = 0.f;
      #pragma unroll
      for (int k = 0; k < K; ++k){ x[k] = nb[k*C] + a[k]; ss += x[k]*x[k]; }
      float rr = ln2g[c] / sqrtf(ss*(1.0f/K) + 1e-6f);
      if (half == 0){
        #pragma unroll
        for (int k = 0; k < K; ++k) xnL[w][k*C + c] = x[k]*rr;
      }
    }
    asm volatile("s_waitcnt lgkmcnt(0)" ::: "memory");
    {
      float gacc = 0.f;
      #pragma unroll
      for (int i = 0; i < 16; ++i){
        int cc = i + half*16;
        gacc += xnL[w][cc] * Wg[cc*C + c];
      }
      gacc += __shfl_xor(gacc, 32);
      float gate = gacc / (1.0f + __expf(-gacc));
      float f[K];
      #pragma unroll
      for (int k = 0; k < K; ++k) f[k] = 0.f;
      #pragma unroll
      for (int i = 0; i < 16; ++i){
        int cc = i + half*16;
        float w1 = W1[cc*C + c];
        #pragma unroll
        for (int k = 0; k < K; ++k) f[k] += xnL[w][k*C + cc] * w1;
      }
      #pragma unroll
      for (int k = 0; k < K; ++k) f[k] += __shfl_xor(f[k], 32);
      if (half == 0){
        #pragma unroll
        for (int k = 0; k < K; ++k) fL[w][k*C + c] = f[k]*gate;
      }
    }
    asm volatile("s_waitcnt lgkmcnt(0)" ::: "memory");
    {
      float o[K];
      #pragma unroll
      for (int k = 0; k < K; ++k) o[k] = 0.f;
      #pragma unroll
      for (int i = 0; i < 16; ++i){
        int cc = i + half*16;
        float w2 = W2[cc*C + c];
        #pragma unroll
        for (int k = 0; k < K; ++k) o[k] += fL[w][k*C + cc] * w2;
      }
      #pragma unroll
      for (int k = 0; k < K; ++k) o[k] += __shfl_xor(o[k], 32);
      if (half == 0){
        float* ob = out_node + (size_t)n*KC + c;
        #pragma unroll
        for (int k = 0; k < K; ++k) ob[k*C] = x[k] + o[k];
      }
    }
    asm volatile("s_waitcnt lgkmcnt(0)" ::: "memory");
  }
}

// ---- 5. edge MLP via MFMA (unchanged)
__global__ __launch_bounds__(256, 2)
void k_edge(const float* __restrict__ node_out, const float* __restrict__ ef,
            const int* __restrict__ src, const int* __restrict__ dst,
            const float* __restrict__ Wf1, const float* __restrict__ bf1,
            const float* __restrict__ Wf2, const float* __restrict__ bf2,
            const float* __restrict__ lng, const float* __restrict__ lnb,
            float* __restrict__ out_edge, int Ee){
  __shared__ f16 ou1[4][32*72];
  int lane = threadIdx.x & 63, w = threadIdx.x >> 6;
  int g = lane >> 4, c = lane & 15;

  f16x8 bw1[4][4];
  #pragma unroll
  for (int t = 0; t < 4; ++t)
    #pragma unroll
    for (int n = 0; n < 4; ++n)
      bw1[t][n] = loadWfrag(Wf1, 32*t + 8*g, 16*n + c);
  f16x8 bw2[2][4];
  #pragma unroll
  for (int t = 0; t < 2; ++t)
    #pragma unroll
    for (int n = 0; n < 4; ++n)
      bw2[t][n] = loadWfrag(Wf2, 32*t + 8*g, 16*n + c);
  float b1v[4], b2v[4], gv[4], bv[4];
  #pragma unroll
  for (int n = 0; n < 4; ++n){
    b1v[n] = bf1[16*n+c]; b2v[n] = bf2[16*n+c];
    gv[n]  = lng[16*n+c]; bv[n]  = lnb[16*n+c];
  }

  f16* o1 = &ou1[w][0];
  int ntile = (Ee + 31) >> 5;
  for (int tb = blockIdx.x*4 + w; tb < ntile; tb += gridDim.x*4){
    int e0 = tb*32;
    int eA0 = min(e0 + c,      Ee-1);
    int eA1 = min(e0 + 16 + c, Ee-1);
    int s0 = src[eA0], s1 = src[eA1], d0 = dst[eA0], d1 = dst[eA1];

    f32x4 acc[2][4];
    #pragma unroll
    for (int m = 0; m < 2; ++m)
      #pragma unroll
      for (int n = 0; n < 4; ++n)
        acc[m][n] = f32x4{b1v[n], b1v[n], b1v[n], b1v[n]};

    {
      const float* p0 = node_out + (size_t)s0*KC + 8*g;
      const float* p1 = node_out + (size_t)s1*KC + 8*g;
      f16x8 a0 = pack8(*(const float4*)p0, *(const float4*)(p0+4));
      f16x8 a1 = pack8(*(const float4*)p1, *(const float4*)(p1+4));
      #pragma unroll
      for (int n = 0; n < 4; ++n){
        acc[0][n] = __builtin_amdgcn_mfma_f32_16x16x32_f16(a0, bw1[0][n], acc[0][n], 0, 0, 0);
        acc[1][n] = __builtin_amdgcn_mfma_f32_16x16x32_f16(a1, bw1[0][n], acc[1][n], 0, 0, 0);
      }
    }
    {
      const float* p0 = node_out + (size_t)d0*KC + 8*g;
      const float* p1 = node_out + (size_t)d1*KC + 8*g;
      f16x8 a0 = pack8(*(const float4*)p0, *(const float4*)(p0+4));
      f16x8 a1 = pack8(*(const float4*)p1, *(const float4*)(p1+4));
      #pragma unroll
      for (int n = 0; n < 4; ++n){
        acc[0][n] = __builtin_amdgcn_mfma_f32_16x16x32_f16(a0, bw1[1][n], acc[0][n], 0, 0, 0);
        acc[1][n] = __builtin_amdgcn_mfma_f32_16x16x32_f16(a1, bw1[1][n], acc[1][n], 0, 0, 0);
      }
    }
    #pragma unroll
    for (int t = 2; t < 4; ++t){
      int koff = (t-2)*32 + 8*g;
      const float* p0 = ef + (size_t)eA0*DE + koff;
      const float* p1 = ef + (size_t)eA1*DE + koff;
      f16x8 a0 = pack8(*(const float4*)p0, *(const float4*)(p0+4));
      f16x8 a1 = pack8(*(const float4*)p1, *(const float4*)(p1+4));
      #pragma unroll
      for (int n = 0; n < 4; ++n){
        acc[0][n] = __builtin_amdgcn_mfma_f32_16x16x32_f16(a0, bw1[t][n], acc[0][n], 0, 0, 0);
        acc[1][n] = __builtin_amdgcn_mfma_f32_16x16x32_f16(a1, bw1[t][n], acc[1][n], 0, 0, 0);
      }
    }

    #pragma unroll
    for (int m = 0; m < 2; ++m)
      #pragma unroll
      for (int n = 0; n < 4; ++n)
        #pragma unroll
        for (int r = 0; r < 4; ++r)
          o1[(16*m + 4*g + r)*72 + 16*n + c] = (f16)fmaxf(acc[m][n][r], 0.f);
    asm volatile("s_waitcnt lgkmcnt(0)" ::: "memory");

    f32x4 acc2[2][4];
    #pragma unroll
    for (int m = 0; m < 2; ++m)
      #pragma unroll
      for (int n = 0; n < 4; ++n)
        acc2[m][n] = f32x4{b2v[n], b2v[n], b2v[n], b2v[n]};
    #pragma unroll
    for (int t = 0; t < 2; ++t){
      f16x8 a20 = *(const f16x8*)(o1 + (     c)*72 + 32*t + 8*g);
      f16x8 a21 = *(const f16x8*)(o1 + (16 + c)*72 + 32*t + 8*g);
      #pragma unroll
      for (int n = 0; n < 4; ++n){
        acc2[0][n] = __builtin_amdgcn_mfma_f32_16x16x32_f16(a20, bw2[t][n], acc2[0][n], 0, 0, 0);
        acc2[1][n] = __builtin_amdgcn_mfma_f32_16x16x32_f16(a21, bw2[t][n], acc2[1][n], 0, 0, 0);
      }
    }

    #pragma unroll
    for (int m = 0; m < 2; ++m){
      #pragma unroll
      for (int r = 0; r < 4; ++r){
        float s = 0.f, q = 0.f;
        #pragma unroll
        for (int n = 0; n < 4; ++n){ float v = acc2[m][n][r]; s += v; q += v*v; }
        s += __shfl_xor(s, 1);  q += __shfl_xor(q, 1);
        s += __shfl_xor(s, 2);  q += __shfl_xor(q, 2);
        s += __shfl_xor(s, 4);  q += __shfl_xor(q, 4);
        s += __shfl_xor(s, 8);  q += __shfl_xor(q, 8);
        float mu = s * (1.0f/DE);
        float var = fmaxf(q * (1.0f/DE) - mu*mu, 0.f);
        float rstd = 1.0f / sqrtf(var + 1e-5f);
        int e = e0 + 16*m + 4*g + r;
        if (e < Ee){
          #pragma unroll
          for (int n = 0; n < 4; ++n){
            float y = (acc2[m][n][r] - mu) * rstd * gv[n] + bv[n];
            size_t off = (size_t)e*DE + 16*n + c;
            out_edge[off] = ef[off] + y;
          }
        }
      }
    }
  }
}

extern "C" void kernel_launch(void* const* d_in, const int* in_sizes, int n_in,
                              void* d_out, int out_size, void* d_ws, size_t ws_size,
                              hipStream_t stream){
  const float* nf  = (const float*)d_in[0];
  const float* ef  = (const float*)d_in[1];
  const int*   ei  = (const int*)d_in[2];
  const float* Wa  = (const float*)d_in[3];
  const float* ba  = (const float*)d_in[4];
  const float* Wv  = (const float*)d_in[5];
  const float* Wo  = (const float*)d_in[6];
  const float* ln1g= (const float*)d_in[7];
  const float* ln2g= (const float*)d_in[8];
  const float* Wg  = (const float*)d_in[9];
  const float* W1  = (const float*)d_in[10];
  const float* W2  = (const float*)d_in[11];
  const float* Wf1 = (const float*)d_in[12];
  const float* bf1 = (const float*)d_in[13];
  const float* Wf2 = (const float*)d_in[14];
  const float* bf2 = (const float*)d_in[15];
  const float* lng = (const float*)d_in[16];
  const float* lnb = (const float*)d_in[17];

  int Nn = in_sizes[0] / KC;     // 20000
  int Ee = in_sizes[2] / 2;      // 200000
  const int* src = ei;
  const int* dst = ei + Ee;

  float* fws    = (float*)d_ws;
  float* zs     = fws;                              // E*H (CSR-ordered)
  float* psb    = zs     + (size_t)Ee*H;            // N*H
  float* pdb    = psb    + (size_t)Nn*H;            // N*H
  u32*   V32    = (u32*)(pdb + (size_t)Nn*H);       // N*192 (fp8)
  int*   counts = (int*)(V32 + (size_t)Nn*192);     // N
  int*   rowptr = counts + Nn;                      // N+1
  int*   rowpos = rowptr + Nn + 1;                  // N
  int*   esrc   = rowpos + Nn;                      // E
  int*   epos   = esrc + Ee;                        // E

  hipMemsetAsync(counts, 0, (size_t)Nn*sizeof(int), stream);

  k_count  <<<(Ee+255)/256, 256, 0, stream>>>(dst, counts, Ee);
  k_scan   <<<1, 1024, 0, stream>>>(counts, rowptr, rowpos, Nn, Ee);
  k_scatter<<<(Ee+255)/256, 256, 0, stream>>>(src, dst, rowpos, esrc, epos, Ee);
  k_value  <<<(Nn+3)/4, 256, 0, stream>>>(nf, ln1g, Wv, Wa, ba, V32, psb, pdb, Nn);
  k_logits <<<1024, 256, 0, stream>>>(ef, src, dst, epos, Wa, psb, pdb, zs, Ee);

  float* out_node = (float*)d_out;
  float* out_edge = out_node + (size_t)Nn*KC;
  k_node<<<(Nn+7)/8, 256, 0, stream>>>(nf, V32, zs, rowptr, esrc,
                                       Wo, ln2g, Wg, W1, W2, out_node, Nn);
  k_edge<<<512, 256, 0, stream>>>(out_node, ef, src, dst, Wf1, bf1, Wf2, bf2,
                                  lng, lnb, out_edge, Ee);
}

// Round 18
// 202.829 us; speedup vs baseline: 1.9190x; 1.9190x over previous
//
#include <hip/hip_runtime.h>
#include <hip/hip_bf16.h>

#define K 9
#define C 32
#define H 8
#define DV 8
#define DE 64
#define DIN 128
#define KC 288   // K*C
#define HD 64    // H*DV
#define MS 576   // K*HD

typedef unsigned short u16;
typedef unsigned int u32;
typedef __fp16 f16;
typedef f16 f16x8 __attribute__((ext_vector_type(8)));
typedef f16 f16x2 __attribute__((ext_vector_type(2)));
typedef float f32x4 __attribute__((ext_vector_type(4)));
typedef float f32x2 __attribute__((ext_vector_type(2)));

__device__ __forceinline__ f16x8 pack8(float4 a, float4 b){
  union { f16x8 v; f16x2 h[4]; } u;
  u.h[0] = __builtin_amdgcn_cvt_pkrtz(a.x, a.y);
  u.h[1] = __builtin_amdgcn_cvt_pkrtz(a.z, a.w);
  u.h[2] = __builtin_amdgcn_cvt_pkrtz(b.x, b.y);
  u.h[3] = __builtin_amdgcn_cvt_pkrtz(b.z, b.w);
  return u.v;
}

__device__ __forceinline__ f16x8 loadWfrag(const float* __restrict__ W, int k0, int col){
  union { f16x8 v; f16x2 h[4]; } u;
  #pragma unroll
  for (int j = 0; j < 4; ++j){
    float x0 = W[(k0 + 2*j    )*DE + col];
    float x1 = W[(k0 + 2*j + 1)*DE + col];
    u.h[j] = __builtin_amdgcn_cvt_pkrtz(x0, x1);
  }
  return u.v;
}

// ---- CSR build
__global__ void k_count(const int* __restrict__ dst, int* __restrict__ counts, int Ee){
  int e = blockIdx.x*blockDim.x + threadIdx.x;
  if (e < Ee) atomicAdd(&counts[dst[e]], 1);
}

__global__ void k_scan(const int* __restrict__ counts, int* __restrict__ rowptr,
                       int* __restrict__ rowpos, int Nn, int Ee){
  __shared__ int part[1024];
  int t = threadIdx.x;
  int cpt = (Nn + 1023) >> 10;
  int base = t*cpt;
  int lsum = 0;
  for (int i = 0; i < cpt; ++i){ int idx = base+i; if (idx < Nn) lsum += counts[idx]; }
  part[t] = lsum; __syncthreads();
  for (int off = 1; off < 1024; off <<= 1){
    int v = (t >= off) ? part[t-off] : 0;
    __syncthreads();
    part[t] += v;
    __syncthreads();
  }
  int run = part[t] - lsum;
  for (int i = 0; i < cpt; ++i){
    int idx = base+i;
    if (idx < Nn){ rowptr[idx] = run; rowpos[idx] = run; run += counts[idx]; }
  }
  if (t == 1023) rowptr[Nn] = Ee;
}

__global__ void k_scatter(const int* __restrict__ src, const int* __restrict__ dst,
                          int* __restrict__ rowpos, int* __restrict__ esrc,
                          int* __restrict__ epos, int Ee){
  int e = blockIdx.x*blockDim.x + threadIdx.x;
  if (e >= Ee) return;
  int pos = atomicAdd(&rowpos[dst[e]], 1);
  esrc[pos] = src[e];
  epos[e] = pos;
}

// ---- 2. per-node (eqnorm fused): V packed fp8-e4m3 [n][3][64]; ps/pd logit halves
__global__ void k_value(const float* __restrict__ nf, const float* __restrict__ ln1g,
                        const float* __restrict__ Wv, const float* __restrict__ Wa,
                        const float* __restrict__ ba,
                        u32* __restrict__ V32, float* __restrict__ psb,
                        float* __restrict__ pdb, int Nn){
  __shared__ float xsL[4][KC];
  __shared__ float scL[4][C];
  int lane = threadIdx.x & 63, w = threadIdx.x >> 6;
  int n = blockIdx.x*4 + w;
  if (n >= Nn) return;
  {
    const float* xb = nf + (size_t)n*KC;
    for (int i = lane; i < KC; i += 64) xsL[w][i] = xb[i];
  }
  asm volatile("s_waitcnt lgkmcnt(0)" ::: "memory");
  if (lane < 32){
    float ss = 0.f;
    #pragma unroll
    for (int k = 0; k < K; ++k){ float v = xsL[w][k*C + lane]; ss += v*v; }
    scL[w][lane] = ln1g[lane] / sqrtf(ss*(1.0f/K) + 1e-6f);
  }
  asm volatile("s_waitcnt lgkmcnt(0)" ::: "memory");
  {
    for (int i = lane; i < KC; i += 64) xsL[w][i] *= scL[w][i & 31];
  }
  asm volatile("s_waitcnt lgkmcnt(0)" ::: "memory");
  int dd = lane;
  float acc[K];
  #pragma unroll
  for (int k = 0; k < K; ++k) acc[k] = 0.f;
  for (int c = 0; c < C; ++c){
    float wvc = Wv[c*HD + dd];
    #pragma unroll
    for (int k = 0; k < K; ++k) acc[k] += xsL[w][k*C + c] * wvc;
  }
  u32 w0 = __builtin_amdgcn_cvt_pk_fp8_f32(acc[0], acc[1], 0, false);
  w0     = __builtin_amdgcn_cvt_pk_fp8_f32(acc[2], acc[3], w0, true);
  u32 w1 = __builtin_amdgcn_cvt_pk_fp8_f32(acc[4], acc[5], 0, false);
  w1     = __builtin_amdgcn_cvt_pk_fp8_f32(acc[6], acc[7], w1, true);
  u32 w2 = __builtin_amdgcn_cvt_pk_fp8_f32(acc[8], 0.f, 0, false);
  u32* vb = V32 + (size_t)n*192 + dd;
  vb[0] = w0; vb[64] = w1; vb[128] = w2;

  int h = lane >> 3, i = lane & 7;
  float ps = 0.f, pd = 0.f;
  #pragma unroll
  for (int t = 0; t < 4; ++t){
    int c = i + t*8;
    float xv = xsL[w][c];
    ps = fmaf(xv, Wa[c*H + h], ps);
    pd = fmaf(xv, Wa[(32+c)*H + h], pd);
  }
  ps += __shfl_xor(ps, 1); pd += __shfl_xor(pd, 1);
  ps += __shfl_xor(ps, 2); pd += __shfl_xor(pd, 2);
  ps += __shfl_xor(ps, 4); pd += __shfl_xor(pd, 4);
  if (i == 0){
    psb[(size_t)n*H + h] = ps + ba[h];
    pdb[(size_t)n*H + h] = pd;
  }
}

// ---- 3. logits -> z written at CSR position (sequential reads in k_node)
__global__ __launch_bounds__(256)
void k_logits(const float* __restrict__ ef, const int* __restrict__ src,
              const int* __restrict__ dst, const int* __restrict__ epos,
              const float* __restrict__ Wa,
              const float* __restrict__ psb, const float* __restrict__ pdb,
              float* __restrict__ zs, int Ee){
  __shared__ float efL[32*66];
  int t = threadIdx.x;
  int h = t & 7, es = t >> 3;
  float w2r[64];
  #pragma unroll
  for (int d = 0; d < 64; ++d) w2r[d] = Wa[(64+d)*H + h];
  for (int e0 = blockIdx.x*32; e0 < Ee; e0 += gridDim.x*32){
    #pragma unroll
    for (int u = 0; u < 4; ++u){
      int idx = u*512 + t*2;
      int row = idx >> 6, col = idx & 63;
      if (e0 + row < Ee){
        float2 v = *(const float2*)&ef[(size_t)(e0+row)*DE + col];
        *(float2*)&efL[row*66 + col] = v;
      }
    }
    __syncthreads();
    int e = e0 + es;
    if (e < Ee){
      const float* er = &efL[es*66];
      float a0=0.f, a1=0.f, a2=0.f, a3=0.f;
      #pragma unroll
      for (int d = 0; d < 64; d += 4){
        a0 = fmaf(er[d+0], w2r[d+0], a0);
        a1 = fmaf(er[d+1], w2r[d+1], a1);
        a2 = fmaf(er[d+2], w2r[d+2], a2);
        a3 = fmaf(er[d+3], w2r[d+3], a3);
      }
      int s = src[e], d0 = dst[e];
      float logit = (a0+a1)+(a2+a3) + psb[(size_t)s*H + h] + pdb[(size_t)d0*H + h];
      zs[(size_t)epos[e]*H + h] = __expf(logit);
    }
    __syncthreads();
  }
}

// ---- 4. gather + node update: R16 body verbatim, ONE WAVE PER BLOCK
//      (no inter-wave coupling exists; finest dispatch granularity -> occupancy)
__global__ __launch_bounds__(64)
void k_node(const float* __restrict__ nf, const u32* __restrict__ V32,
            const float* __restrict__ zs, const int* __restrict__ rowptr,
            const int* __restrict__ esrc,
            const float* __restrict__ Wo, const float* __restrict__ ln2g,
            const float* __restrict__ Wg, const float* __restrict__ W1,
            const float* __restrict__ W2, float* __restrict__ out_node, int Nn){
  __shared__ float msgL[MS];
  __shared__ float xnL[KC];
  __shared__ float fL[KC];
  int lane = threadIdx.x & 63;
  int n = blockIdx.x;
  if (n >= Nn) return;
  {
    int r0 = rowptr[n], r1 = rowptr[n+1];
    int h = lane >> 3;
    float den = 0.f;
    float acc[K];
    #pragma unroll
    for (int k = 0; k < K; ++k) acc[k] = 0.f;
    for (int base = r0; base < r1; base += 64){
      int cnt = min(64, r1 - base);
      int my_s = (lane < cnt) ? esrc[base + lane] : 0;   // one coalesced load
      #pragma unroll 2
      for (int j = 0; j < cnt; ++j){
        int s = __shfl(my_s, j);                         // register broadcast
        float z = zs[(size_t)(base + j)*H + h];
        den += z;
        const u32* vb = V32 + (size_t)s*192 + lane;
        u32 w0 = vb[0], w1 = vb[64], w2 = vb[128];
        f32x2 p01 = __builtin_amdgcn_cvt_pk_f32_fp8(w0, false);
        f32x2 p23 = __builtin_amdgcn_cvt_pk_f32_fp8(w0, true);
        f32x2 p45 = __builtin_amdgcn_cvt_pk_f32_fp8(w1, false);
        f32x2 p67 = __builtin_amdgcn_cvt_pk_f32_fp8(w1, true);
        float p8  = __builtin_amdgcn_cvt_f32_fp8(w2, 0);
        acc[0] = fmaf(z, p01[0], acc[0]);
        acc[1] = fmaf(z, p01[1], acc[1]);
        acc[2] = fmaf(z, p23[0], acc[2]);
        acc[3] = fmaf(z, p23[1], acc[3]);
        acc[4] = fmaf(z, p45[0], acc[4]);
        acc[5] = fmaf(z, p45[1], acc[5]);
        acc[6] = fmaf(z, p67[0], acc[6]);
        acc[7] = fmaf(z, p67[1], acc[7]);
        acc[8] = fmaf(z, p8,     acc[8]);
      }
    }
    float inv = 1.0f / (den + 1e-9f);
    #pragma unroll
    for (int k = 0; k < K; ++k) msgL[k*HD + lane] = acc[k]*inv;
  }
  asm volatile("s_waitcnt lgkmcnt(0)" ::: "memory");   // same-wave LDS visibility
  // ---- phase 2: ALL 64 lanes; lane halves split the reduction dims, shfl_xor(32) combines
  int c = lane & 31, half = lane >> 5;
  float x[K];
  {
    float a[K];
    #pragma unroll
    for (int k = 0; k < K; ++k) a[k] = 0.f;
    for (int dd = 0; dd < 32; ++dd){
      int d = dd + half*32;
      float wo = Wo[d*C + c];
      #pragma unroll
      for (int k = 0; k < K; ++k) a[k] += msgL[k*HD + d] * wo;
    }
    #pragma unroll
    for (int k = 0; k < K; ++k) a[k] += __shfl_xor(a[k], 32);
    const float* nb = nf + (size_t)n*KC + c;
    float ss = 0.f;
    #pragma unroll
    for (int k = 0; k < K; ++k){ x[k] = nb[k*C] + a[k]; ss += x[k]*x[k]; }
    float rr = ln2g[c] / sqrtf(ss*(1.0f/K) + 1e-6f);
    if (half == 0){
      #pragma unroll
      for (int k = 0; k < K; ++k) xnL[k*C + c] = x[k]*rr;
    }
  }
  asm volatile("s_waitcnt lgkmcnt(0)" ::: "memory");
  {
    float gacc = 0.f;
    #pragma unroll
    for (int i = 0; i < 16; ++i){
      int cc = i + half*16;
      gacc += xnL[cc] * Wg[cc*C + c];
    }
    gacc += __shfl_xor(gacc, 32);
    float gate = gacc / (1.0f + __expf(-gacc));
    float f[K];
    #pragma unroll
    for (int k = 0; k < K; ++k) f[k] = 0.f;
    #pragma unroll
    for (int i = 0; i < 16; ++i){
      int cc = i + half*16;
      float w1 = W1[cc*C + c];
      #pragma unroll
      for (int k = 0; k < K; ++k) f[k] += xnL[k*C + cc] * w1;
    }
    #pragma unroll
    for (int k = 0; k < K; ++k) f[k] += __shfl_xor(f[k], 32);
    if (half == 0){
      #pragma unroll
      for (int k = 0; k < K; ++k) fL[k*C + c] = f[k]*gate;
    }
  }
  asm volatile("s_waitcnt lgkmcnt(0)" ::: "memory");
  {
    float o[K];
    #pragma unroll
    for (int k = 0; k < K; ++k) o[k] = 0.f;
    #pragma unroll
    for (int i = 0; i < 16; ++i){
      int cc = i + half*16;
      float w2 = W2[cc*C + c];
      #pragma unroll
      for (int k = 0; k < K; ++k) o[k] += fL[k*C + cc] * w2;
    }
    #pragma unroll
    for (int k = 0; k < K; ++k) o[k] += __shfl_xor(o[k], 32);
    if (half == 0){
      float* ob = out_node + (size_t)n*KC + c;
      #pragma unroll
      for (int k = 0; k < K; ++k) ob[k*C] = x[k] + o[k];
    }
  }
}

// ---- 5. edge MLP via MFMA (unchanged)
__global__ __launch_bounds__(256, 2)
void k_edge(const float* __restrict__ node_out, const float* __restrict__ ef,
            const int* __restrict__ src, const int* __restrict__ dst,
            const float* __restrict__ Wf1, const float* __restrict__ bf1,
            const float* __restrict__ Wf2, const float* __restrict__ bf2,
            const float* __restrict__ lng, const float* __restrict__ lnb,
            float* __restrict__ out_edge, int Ee){
  __shared__ f16 ou1[4][32*72];
  int lane = threadIdx.x & 63, w = threadIdx.x >> 6;
  int g = lane >> 4, c = lane & 15;

  f16x8 bw1[4][4];
  #pragma unroll
  for (int t = 0; t < 4; ++t)
    #pragma unroll
    for (int n = 0; n < 4; ++n)
      bw1[t][n] = loadWfrag(Wf1, 32*t + 8*g, 16*n + c);
  f16x8 bw2[2][4];
  #pragma unroll
  for (int t = 0; t < 2; ++t)
    #pragma unroll
    for (int n = 0; n < 4; ++n)
      bw2[t][n] = loadWfrag(Wf2, 32*t + 8*g, 16*n + c);
  float b1v[4], b2v[4], gv[4], bv[4];
  #pragma unroll
  for (int n = 0; n < 4; ++n){
    b1v[n] = bf1[16*n+c]; b2v[n] = bf2[16*n+c];
    gv[n]  = lng[16*n+c]; bv[n]  = lnb[16*n+c];
  }

  f16* o1 = &ou1[w][0];
  int ntile = (Ee + 31) >> 5;
  for (int tb = blockIdx.x*4 + w; tb < ntile; tb += gridDim.x*4){
    int e0 = tb*32;
    int eA0 = min(e0 + c,      Ee-1);
    int eA1 = min(e0 + 16 + c, Ee-1);
    int s0 = src[eA0], s1 = src[eA1], d0 = dst[eA0], d1 = dst[eA1];

    f32x4 acc[2][4];
    #pragma unroll
    for (int m = 0; m < 2; ++m)
      #pragma unroll
      for (int n = 0; n < 4; ++n)
        acc[m][n] = f32x4{b1v[n], b1v[n], b1v[n], b1v[n]};

    {
      const float* p0 = node_out + (size_t)s0*KC + 8*g;
      const float* p1 = node_out + (size_t)s1*KC + 8*g;
      f16x8 a0 = pack8(*(const float4*)p0, *(const float4*)(p0+4));
      f16x8 a1 = pack8(*(const float4*)p1, *(const float4*)(p1+4));
      #pragma unroll
      for (int n = 0; n < 4; ++n){
        acc[0][n] = __builtin_amdgcn_mfma_f32_16x16x32_f16(a0, bw1[0][n], acc[0][n], 0, 0, 0);
        acc[1][n] = __builtin_amdgcn_mfma_f32_16x16x32_f16(a1, bw1[0][n], acc[1][n], 0, 0, 0);
      }
    }
    {
      const float* p0 = node_out + (size_t)d0*KC + 8*g;
      const float* p1 = node_out + (size_t)d1*KC + 8*g;
      f16x8 a0 = pack8(*(const float4*)p0, *(const float4*)(p0+4));
      f16x8 a1 = pack8(*(const float4*)p1, *(const float4*)(p1+4));
      #pragma unroll
      for (int n = 0; n < 4; ++n){
        acc[0][n] = __builtin_amdgcn_mfma_f32_16x16x32_f16(a0, bw1[1][n], acc[0][n], 0, 0, 0);
        acc[1][n] = __builtin_amdgcn_mfma_f32_16x16x32_f16(a1, bw1[1][n], acc[1][n], 0, 0, 0);
      }
    }
    #pragma unroll
    for (int t = 2; t < 4; ++t){
      int koff = (t-2)*32 + 8*g;
      const float* p0 = ef + (size_t)eA0*DE + koff;
      const float* p1 = ef + (size_t)eA1*DE + koff;
      f16x8 a0 = pack8(*(const float4*)p0, *(const float4*)(p0+4));
      f16x8 a1 = pack8(*(const float4*)p1, *(const float4*)(p1+4));
      #pragma unroll
      for (int n = 0; n < 4; ++n){
        acc[0][n] = __builtin_amdgcn_mfma_f32_16x16x32_f16(a0, bw1[t][n], acc[0][n], 0, 0, 0);
        acc[1][n] = __builtin_amdgcn_mfma_f32_16x16x32_f16(a1, bw1[t][n], acc[1][n], 0, 0, 0);
      }
    }

    #pragma unroll
    for (int m = 0; m < 2; ++m)
      #pragma unroll
      for (int n = 0; n < 4; ++n)
        #pragma unroll
        for (int r = 0; r < 4; ++r)
          o1[(16*m + 4*g + r)*72 + 16*n + c] = (f16)fmaxf(acc[m][n][r], 0.f);
    asm volatile("s_waitcnt lgkmcnt(0)" ::: "memory");

    f32x4 acc2[2][4];
    #pragma unroll
    for (int m = 0; m < 2; ++m)
      #pragma unroll
      for (int n = 0; n < 4; ++n)
        acc2[m][n] = f32x4{b2v[n], b2v[n], b2v[n], b2v[n]};
    #pragma unroll
    for (int t = 0; t < 2; ++t){
      f16x8 a20 = *(const f16x8*)(o1 + (     c)*72 + 32*t + 8*g);
      f16x8 a21 = *(const f16x8*)(o1 + (16 + c)*72 + 32*t + 8*g);
      #pragma unroll
      for (int n = 0; n < 4; ++n){
        acc2[0][n] = __builtin_amdgcn_mfma_f32_16x16x32_f16(a20, bw2[t][n], acc2[0][n], 0, 0, 0);
        acc2[1][n] = __builtin_amdgcn_mfma_f32_16x16x32_f16(a21, bw2[t][n], acc2[1][n], 0, 0, 0);
      }
    }

    #pragma unroll
    for (int m = 0; m < 2; ++m){
      #pragma unroll
      for (int r = 0; r < 4; ++r){
        float s = 0.f, q = 0.f;
        #pragma unroll
        for (int n = 0; n < 4; ++n){ float v = acc2[m][n][r]; s += v; q += v*v; }
        s += __shfl_xor(s, 1);  q += __shfl_xor(q, 1);
        s += __shfl_xor(s, 2);  q += __shfl_xor(q, 2);
        s += __shfl_xor(s, 4);  q += __shfl_xor(q, 4);
        s += __shfl_xor(s, 8);  q += __shfl_xor(q, 8);
        float mu = s * (1.0f/DE);
        float var = fmaxf(q * (1.0f/DE) - mu*mu, 0.f);
        float rstd = 1.0f / sqrtf(var + 1e-5f);
        int e = e0 + 16*m + 4*g + r;
        if (e < Ee){
          #pragma unroll
          for (int n = 0; n < 4; ++n){
            float y = (acc2[m][n][r] - mu) * rstd * gv[n] + bv[n];
            size_t off = (size_t)e*DE + 16*n + c;
            out_edge[off] = ef[off] + y;
          }
        }
      }
    }
  }
}

extern "C" void kernel_launch(void* const* d_in, const int* in_sizes, int n_in,
                              void* d_out, int out_size, void* d_ws, size_t ws_size,
                              hipStream_t stream){
  const float* nf  = (const float*)d_in[0];
  const float* ef  = (const float*)d_in[1];
  const int*   ei  = (const int*)d_in[2];
  const float* Wa  = (const float*)d_in[3];
  const float* ba  = (const float*)d_in[4];
  const float* Wv  = (const float*)d_in[5];
  const float* Wo  = (const float*)d_in[6];
  const float* ln1g= (const float*)d_in[7];
  const float* ln2g= (const float*)d_in[8];
  const float* Wg  = (const float*)d_in[9];
  const float* W1  = (const float*)d_in[10];
  const float* W2  = (const float*)d_in[11];
  const float* Wf1 = (const float*)d_in[12];
  const float* bf1 = (const float*)d_in[13];
  const float* Wf2 = (const float*)d_in[14];
  const float* bf2 = (const float*)d_in[15];
  const float* lng = (const float*)d_in[16];
  const float* lnb = (const float*)d_in[17];

  int Nn = in_sizes[0] / KC;     // 20000
  int Ee = in_sizes[2] / 2;      // 200000
  const int* src = ei;
  const int* dst = ei + Ee;

  float* fws    = (float*)d_ws;
  float* zs     = fws;                              // E*H (CSR-ordered)
  float* psb    = zs     + (size_t)Ee*H;            // N*H
  float* pdb    = psb    + (size_t)Nn*H;            // N*H
  u32*   V32    = (u32*)(pdb + (size_t)Nn*H);       // N*192 (fp8)
  int*   counts = (int*)(V32 + (size_t)Nn*192);     // N
  int*   rowptr = counts + Nn;                      // N+1
  int*   rowpos = rowptr + Nn + 1;                  // N
  int*   esrc   = rowpos + Nn;                      // E
  int*   epos   = esrc + Ee;                        // E

  hipMemsetAsync(counts, 0, (size_t)Nn*sizeof(int), stream);

  k_count  <<<(Ee+255)/256, 256, 0, stream>>>(dst, counts, Ee);
  k_scan   <<<1, 1024, 0, stream>>>(counts, rowptr, rowpos, Nn, Ee);
  k_scatter<<<(Ee+255)/256, 256, 0, stream>>>(src, dst, rowpos, esrc, epos, Ee);
  k_value  <<<(Nn+3)/4, 256, 0, stream>>>(nf, ln1g, Wv, Wa, ba, V32, psb, pdb, Nn);
  k_logits <<<1024, 256, 0, stream>>>(ef, src, dst, epos, Wa, psb, pdb, zs, Ee);

  float* out_node = (float*)d_out;
  float* out_edge = out_node + (size_t)Nn*KC;
  k_node<<<Nn, 64, 0, stream>>>(nf, V32, zs, rowptr, esrc,
                                Wo, ln2g, Wg, W1, W2, out_node, Nn);
  k_edge<<<512, 256, 0, stream>>>(out_node, ef, src, dst, Wf1, bf1, Wf2, bf2,
                                  lng, lnb, out_edge, Ee);
}